// Round 1
// baseline (1148.622 us; speedup 1.0000x reference)
//
#include <hip/hip_runtime.h>

#define Bc 16
#define Sc 512
#define Dc 1024
#define Hc 16
#define DHc 64

// ---------------------------------------------------------------------------
// h = hidden + (W_in*padmask)[in_degree] + (W_out*padmask)[out_degree]
// one block per (b,s) row; 256 threads x float4 = 1024 floats
// ---------------------------------------------------------------------------
__global__ __launch_bounds__(256) void k_pos_add(
    const float* __restrict__ hidden, const int* __restrict__ ind,
    const int* __restrict__ outd, const float* __restrict__ Win,
    const float* __restrict__ Wout, float* __restrict__ h) {
  int row = blockIdx.x;
  int t = threadIdx.x;
  int id = ind[row], od = outd[row];
  float fi = (id != 0) ? 1.f : 0.f;  // padding_idx=0 -> row 0 zeroed
  float fo = (od != 0) ? 1.f : 0.f;
  float4 a = ((const float4*)(hidden + (size_t)row * Dc))[t];
  float4 x = ((const float4*)(Win + (size_t)id * Dc))[t];
  float4 y = ((const float4*)(Wout + (size_t)od * Dc))[t];
  float4 r;
  r.x = a.x + fi * x.x + fo * y.x;
  r.y = a.y + fi * x.y + fo * y.y;
  r.z = a.z + fi * x.z + fo * y.z;
  r.w = a.w + fi * x.w + fo * y.w;
  ((float4*)(h + (size_t)row * Dc))[t] = r;
}

// ---------------------------------------------------------------------------
// C = A[8192,1024] @ W[1024,1024] + bias ; z in {0,1,2} selects q/k/v
// 64x64 tile, BK=16, 256 threads, 4x4 microtile
// ---------------------------------------------------------------------------
__global__ __launch_bounds__(256) void k_gemm_qkv(
    const float* __restrict__ A,
    const float* __restrict__ Wq, const float* __restrict__ bq,
    const float* __restrict__ Wk, const float* __restrict__ bk,
    const float* __restrict__ Wv, const float* __restrict__ bv,
    float* __restrict__ Qo, float* __restrict__ Ko, float* __restrict__ Vo) {
  const float* W;
  const float* bias;
  float* C;
  if (blockIdx.z == 0) { W = Wq; bias = bq; C = Qo; }
  else if (blockIdx.z == 1) { W = Wk; bias = bk; C = Ko; }
  else { W = Wv; bias = bv; C = Vo; }
  __shared__ float As[16][64];  // As[k][m]
  __shared__ float Bs[16][64];  // Bs[k][n]
  int tid = threadIdx.x;
  int tx = tid & 15, ty = tid >> 4;
  int m0 = blockIdx.y * 64, n0 = blockIdx.x * 64;
  float acc[4][4] = {};
  for (int k0 = 0; k0 < Dc; k0 += 16) {
    int ar = tid >> 2, ac = (tid & 3) * 4;
    float4 av = *(const float4*)(A + (size_t)(m0 + ar) * Dc + k0 + ac);
    As[ac + 0][ar] = av.x;
    As[ac + 1][ar] = av.y;
    As[ac + 2][ar] = av.z;
    As[ac + 3][ar] = av.w;
    int br = tid >> 4, bc = (tid & 15) * 4;
    float4 bw = *(const float4*)(W + (size_t)(k0 + br) * Dc + n0 + bc);
    *(float4*)&Bs[br][bc] = bw;
    __syncthreads();
#pragma unroll
    for (int kk = 0; kk < 16; ++kk) {
      float a0 = As[kk][ty * 4 + 0];
      float a1 = As[kk][ty * 4 + 1];
      float a2 = As[kk][ty * 4 + 2];
      float a3 = As[kk][ty * 4 + 3];
      float4 b4 = *(float4*)&Bs[kk][tx * 4];
      acc[0][0] += a0 * b4.x; acc[0][1] += a0 * b4.y; acc[0][2] += a0 * b4.z; acc[0][3] += a0 * b4.w;
      acc[1][0] += a1 * b4.x; acc[1][1] += a1 * b4.y; acc[1][2] += a1 * b4.z; acc[1][3] += a1 * b4.w;
      acc[2][0] += a2 * b4.x; acc[2][1] += a2 * b4.y; acc[2][2] += a2 * b4.z; acc[2][3] += a2 * b4.w;
      acc[3][0] += a3 * b4.x; acc[3][1] += a3 * b4.y; acc[3][2] += a3 * b4.z; acc[3][3] += a3 * b4.w;
    }
    __syncthreads();
  }
  float4 bb = *(const float4*)(bias + n0 + tx * 4);
#pragma unroll
  for (int i = 0; i < 4; ++i) {
    float4 r;
    r.x = acc[i][0] + bb.x;
    r.y = acc[i][1] + bb.y;
    r.z = acc[i][2] + bb.z;
    r.w = acc[i][3] + bb.w;
    *(float4*)(C + (size_t)(m0 + ty * 4 + i) * Dc + n0 + tx * 4) = r;
  }
}

// ---------------------------------------------------------------------------
// scores[b,h,q,k] = (Q[b,h,q,:].K[b,h,k,:])/8 + Wspe[spe[b,q,k]][h] + mask[b,k]
// per block: one (b,h), 64x64 output tile, full K=64
// ---------------------------------------------------------------------------
__global__ __launch_bounds__(256) void k_scores(
    const float* __restrict__ Q, const float* __restrict__ K,
    const int* __restrict__ spe, const float* __restrict__ Wspe,
    const float* __restrict__ mask, float* __restrict__ probs) {
  int bh = blockIdx.z;
  int b = bh >> 4, h = bh & 15;
  int q0 = blockIdx.y * 64, k0 = blockIdx.x * 64;
  __shared__ float Qs[64][64];   // [qrow][dh]
  __shared__ float Kst[64][64];  // [dh][kcol] (transposed on load)
  int tid = threadIdx.x;
  for (int i = tid; i < 64 * 16; i += 256) {
    int row = i >> 4, c4 = (i & 15) * 4;
    float4 v = *(const float4*)(Q + (size_t)(b * Sc + q0 + row) * Dc + h * DHc + c4);
    *(float4*)&Qs[row][c4] = v;
  }
  for (int i = tid; i < 64 * 16; i += 256) {
    int row = i >> 4, c4 = (i & 15) * 4;
    float4 v = *(const float4*)(K + (size_t)(b * Sc + k0 + row) * Dc + h * DHc + c4);
    Kst[c4 + 0][row] = v.x;
    Kst[c4 + 1][row] = v.y;
    Kst[c4 + 2][row] = v.z;
    Kst[c4 + 3][row] = v.w;
  }
  __syncthreads();
  int tx = tid & 15, ty = tid >> 4;
  float acc[4][4] = {};
#pragma unroll 16
  for (int dh = 0; dh < 64; ++dh) {
    float a0 = Qs[ty * 4 + 0][dh];
    float a1 = Qs[ty * 4 + 1][dh];
    float a2 = Qs[ty * 4 + 2][dh];
    float a3 = Qs[ty * 4 + 3][dh];
    float4 b4 = *(float4*)&Kst[dh][tx * 4];
    acc[0][0] += a0 * b4.x; acc[0][1] += a0 * b4.y; acc[0][2] += a0 * b4.z; acc[0][3] += a0 * b4.w;
    acc[1][0] += a1 * b4.x; acc[1][1] += a1 * b4.y; acc[1][2] += a1 * b4.z; acc[1][3] += a1 * b4.w;
    acc[2][0] += a2 * b4.x; acc[2][1] += a2 * b4.y; acc[2][2] += a2 * b4.z; acc[2][3] += a2 * b4.w;
    acc[3][0] += a3 * b4.x; acc[3][1] += a3 * b4.y; acc[3][2] += a3 * b4.z; acc[3][3] += a3 * b4.w;
  }
  const float scale = 0.125f;  // 1/sqrt(64)
  float4 mk = *(const float4*)(mask + b * Sc + k0 + tx * 4);
#pragma unroll
  for (int i = 0; i < 4; ++i) {
    int qrow = q0 + ty * 4 + i;
    int4 sp = *(const int4*)(spe + ((size_t)b * Sc + qrow) * Sc + k0 + tx * 4);
    float4 r;
    r.x = acc[i][0] * scale + Wspe[sp.x * Hc + h] + mk.x;
    r.y = acc[i][1] * scale + Wspe[sp.y * Hc + h] + mk.y;
    r.z = acc[i][2] * scale + Wspe[sp.z * Hc + h] + mk.z;
    r.w = acc[i][3] * scale + Wspe[sp.w * Hc + h] + mk.w;
    *(float4*)(probs + ((size_t)bh * Sc + qrow) * Sc + k0 + tx * 4) = r;
  }
}

// ---------------------------------------------------------------------------
// in-place row softmax over last dim (512); one wave per row
// ---------------------------------------------------------------------------
__global__ __launch_bounds__(256) void k_softmax(float* __restrict__ probs) {
  size_t row = ((size_t)blockIdx.x * 256 + threadIdx.x) >> 6;
  int lane = threadIdx.x & 63;
  float* p = probs + row * Sc;
  float4 x0 = ((float4*)p)[lane];
  float4 x1 = ((float4*)p)[lane + 64];
  float m = fmaxf(fmaxf(fmaxf(x0.x, x0.y), fmaxf(x0.z, x0.w)),
                  fmaxf(fmaxf(x1.x, x1.y), fmaxf(x1.z, x1.w)));
#pragma unroll
  for (int o = 32; o; o >>= 1) m = fmaxf(m, __shfl_xor(m, o));
  x0.x = __expf(x0.x - m); x0.y = __expf(x0.y - m);
  x0.z = __expf(x0.z - m); x0.w = __expf(x0.w - m);
  x1.x = __expf(x1.x - m); x1.y = __expf(x1.y - m);
  x1.z = __expf(x1.z - m); x1.w = __expf(x1.w - m);
  float s = x0.x + x0.y + x0.z + x0.w + x1.x + x1.y + x1.z + x1.w;
#pragma unroll
  for (int o = 32; o; o >>= 1) s += __shfl_xor(s, o);
  float r = 1.f / s;
  x0.x *= r; x0.y *= r; x0.z *= r; x0.w *= r;
  x1.x *= r; x1.y *= r; x1.z *= r; x1.w *= r;
  ((float4*)p)[lane] = x0;
  ((float4*)p)[lane + 64] = x1;
}

// ---------------------------------------------------------------------------
// ctx[b,q,h*64+dh] = sum_k probs[b,h,q,k] * V[b,k,h*64+dh]
// per block: one (b,h), 64 q-rows x full 64 dh, K chunked by 64
// ---------------------------------------------------------------------------
__global__ __launch_bounds__(256) void k_pv(
    const float* __restrict__ probs, const float* __restrict__ V,
    float* __restrict__ ctx) {
  int bh = blockIdx.z;
  int b = bh >> 4, h = bh & 15;
  int q0 = blockIdx.x * 64;
  __shared__ float Ps[64][64];  // [qrow][kk]
  __shared__ float Vs[64][64];  // [kk][dh]
  int tid = threadIdx.x;
  int tx = tid & 15, ty = tid >> 4;
  float acc[4][4] = {};
  for (int k0 = 0; k0 < Sc; k0 += 64) {
    for (int i = tid; i < 64 * 16; i += 256) {
      int row = i >> 4, c4 = (i & 15) * 4;
      *(float4*)&Ps[row][c4] =
          *(const float4*)(probs + ((size_t)bh * Sc + q0 + row) * Sc + k0 + c4);
      *(float4*)&Vs[row][c4] =
          *(const float4*)(V + (size_t)(b * Sc + k0 + row) * Dc + h * DHc + c4);
    }
    __syncthreads();
#pragma unroll 16
    for (int kk = 0; kk < 64; ++kk) {
      float a0 = Ps[ty * 4 + 0][kk];
      float a1 = Ps[ty * 4 + 1][kk];
      float a2 = Ps[ty * 4 + 2][kk];
      float a3 = Ps[ty * 4 + 3][kk];
      float4 b4 = *(float4*)&Vs[kk][tx * 4];
      acc[0][0] += a0 * b4.x; acc[0][1] += a0 * b4.y; acc[0][2] += a0 * b4.z; acc[0][3] += a0 * b4.w;
      acc[1][0] += a1 * b4.x; acc[1][1] += a1 * b4.y; acc[1][2] += a1 * b4.z; acc[1][3] += a1 * b4.w;
      acc[2][0] += a2 * b4.x; acc[2][1] += a2 * b4.y; acc[2][2] += a2 * b4.z; acc[2][3] += a2 * b4.w;
      acc[3][0] += a3 * b4.x; acc[3][1] += a3 * b4.y; acc[3][2] += a3 * b4.z; acc[3][3] += a3 * b4.w;
    }
    __syncthreads();
  }
#pragma unroll
  for (int i = 0; i < 4; ++i) {
    *(float4*)(ctx + (size_t)(b * Sc + q0 + ty * 4 + i) * Dc + h * DHc + tx * 4) =
        make_float4(acc[i][0], acc[i][1], acc[i][2], acc[i][3]);
  }
}

extern "C" void kernel_launch(void* const* d_in, const int* in_sizes, int n_in,
                              void* d_out, int out_size, void* d_ws, size_t ws_size,
                              hipStream_t stream) {
  const float* hidden = (const float*)d_in[0];
  const float* amask = (const float*)d_in[1];
  // d_in[2] = if_2d (always 1 -> 2D branch); d_in[6]/d_in[7] unused in 2D path
  const int* ind = (const int*)d_in[3];
  const int* outd = (const int*)d_in[4];
  const int* spe = (const int*)d_in[5];
  const float* Wq = (const float*)d_in[8];
  const float* bq = (const float*)d_in[9];
  const float* Wk = (const float*)d_in[10];
  const float* bk = (const float*)d_in[11];
  const float* Wv = (const float*)d_in[12];
  const float* bv = (const float*)d_in[13];
  const float* Win = (const float*)d_in[14];
  const float* Wout = (const float*)d_in[15];
  const float* Wspe = (const float*)d_in[16];

  float* ws = (float*)d_ws;
  const size_t BSD = (size_t)Bc * Sc * Dc;  // 8388608
  float* h = ws;
  float* Q = ws + BSD;
  float* K = ws + 2 * BSD;
  float* V = ws + 3 * BSD;
  float* ctx = (float*)d_out;
  float* probs = (float*)d_out + BSD;

  k_pos_add<<<dim3(Bc * Sc), 256, 0, stream>>>(hidden, ind, outd, Win, Wout, h);
  k_gemm_qkv<<<dim3(16, 128, 3), 256, 0, stream>>>(h, Wq, bq, Wk, bk, Wv, bv, Q, K, V);
  k_scores<<<dim3(8, 8, Bc * Hc), 256, 0, stream>>>(Q, K, spe, Wspe, amask, probs);
  k_softmax<<<dim3((Bc * Hc * Sc) / 4), 256, 0, stream>>>(probs);
  k_pv<<<dim3(8, 1, Bc * Hc), 256, 0, stream>>>(probs, V, ctx);
}

// Round 2
// 555.131 us; speedup vs baseline: 2.0691x; 2.0691x over previous
//
#include <hip/hip_runtime.h>

#define Bc 16
#define Sc 512
#define Dc 1024
#define Hc 16
#define DHc 64

typedef __attribute__((ext_vector_type(8))) __bf16 bf16x8;
typedef __attribute__((ext_vector_type(4))) float f32x4;

static __device__ __forceinline__ unsigned short f2bf(float f) {
  unsigned int u = __builtin_bit_cast(unsigned int, f);
  unsigned int r = (u + 0x7fffu + ((u >> 16) & 1u)) >> 16;  // RNE
  return (unsigned short)r;
}

// ---------------------------------------------------------------------------
// h_bf16 = bf16( hidden + (W_in*padmask)[in_degree] + (W_out*padmask)[out_degree] )
// one block per (b,s) row; 256 threads x 4 floats
// ---------------------------------------------------------------------------
__global__ __launch_bounds__(256) void k_pos_add(
    const float* __restrict__ hidden, const int* __restrict__ ind,
    const int* __restrict__ outd, const float* __restrict__ Win,
    const float* __restrict__ Wout, unsigned short* __restrict__ hbf) {
  int row = blockIdx.x;
  int t = threadIdx.x;
  int id = ind[row], od = outd[row];
  float fi = (id != 0) ? 1.f : 0.f;  // padding_idx=0 -> row 0 zeroed
  float fo = (od != 0) ? 1.f : 0.f;
  float4 a = ((const float4*)(hidden + (size_t)row * Dc))[t];
  float4 x = ((const float4*)(Win + (size_t)id * Dc))[t];
  float4 y = ((const float4*)(Wout + (size_t)od * Dc))[t];
  ushort4 r;
  r.x = f2bf(a.x + fi * x.x + fo * y.x);
  r.y = f2bf(a.y + fi * x.y + fo * y.y);
  r.z = f2bf(a.z + fi * x.z + fo * y.z);
  r.w = f2bf(a.w + fi * x.w + fo * y.w);
  ((ushort4*)(hbf + (size_t)row * Dc))[t] = r;
}

// ---------------------------------------------------------------------------
// Wt[n][k] = bf16(W[k][n]) for q,k,v — LDS-tiled transpose + convert
// ---------------------------------------------------------------------------
__global__ __launch_bounds__(256) void k_wt(
    const float* __restrict__ Wq, const float* __restrict__ Wk,
    const float* __restrict__ Wv, unsigned short* __restrict__ Wtq,
    unsigned short* __restrict__ Wtk, unsigned short* __restrict__ Wtv) {
  const float* W = blockIdx.z == 0 ? Wq : blockIdx.z == 1 ? Wk : Wv;
  unsigned short* Wt = blockIdx.z == 0 ? Wtq : blockIdx.z == 1 ? Wtk : Wtv;
  __shared__ float tile[64][65];
  int k0 = blockIdx.y * 64, n0 = blockIdx.x * 64;
  int r = threadIdx.x >> 4, c4 = (threadIdx.x & 15) * 4;
  for (int rr = r; rr < 64; rr += 16) {
    float4 v = *(const float4*)(W + (size_t)(k0 + rr) * Dc + n0 + c4);
    tile[rr][c4 + 0] = v.x;
    tile[rr][c4 + 1] = v.y;
    tile[rr][c4 + 2] = v.z;
    tile[rr][c4 + 3] = v.w;
  }
  __syncthreads();
  for (int rr = r; rr < 64; rr += 16) {
    ushort4 o;
    o.x = f2bf(tile[c4 + 0][rr]);
    o.y = f2bf(tile[c4 + 1][rr]);
    o.z = f2bf(tile[c4 + 2][rr]);
    o.w = f2bf(tile[c4 + 3][rr]);
    *(ushort4*)(Wt + (size_t)(n0 + rr) * Dc + k0 + c4) = o;
  }
}

// ---------------------------------------------------------------------------
// C[8192,1024] = bf16 MFMA GEMM: hbf[M,K] @ Wt[N,K]^T + bias, fp32 out.
// 128x128 tile, BK=32, 4 waves, each wave 64x64 (4x4 frags of 16x16x32).
// global_load_lds width=16 staging, linear LDS layout.
// ---------------------------------------------------------------------------
__global__ __launch_bounds__(256) void k_gemm_mfma(
    const unsigned short* __restrict__ hbf,
    const unsigned short* __restrict__ Wtq, const float* __restrict__ bq,
    const unsigned short* __restrict__ Wtk, const float* __restrict__ bk,
    const unsigned short* __restrict__ Wtv, const float* __restrict__ bv,
    float* __restrict__ Qo, float* __restrict__ Ko, float* __restrict__ Vo) {
  const unsigned short* Wt;
  const float* bias;
  float* C;
  if (blockIdx.z == 0) { Wt = Wtq; bias = bq; C = Qo; }
  else if (blockIdx.z == 1) { Wt = Wtk; bias = bk; C = Ko; }
  else { Wt = Wtv; bias = bv; C = Vo; }

  __shared__ __align__(16) unsigned short As[128 * 32];  // [row][k] 64B rows
  __shared__ __align__(16) unsigned short Bs[128 * 32];  // [col][k]

  int tid = threadIdx.x, lane = tid & 63, wave = tid >> 6;
  int m0 = blockIdx.y * 128, n0 = blockIdx.x * 128;
  int wr = wave >> 1, wc = wave & 1;

  f32x4 acc[4][4] = {};

  // staging: per K-step wave handles chunks {wave, wave+4}; chunk = 16 rows
  int srow = lane >> 2;          // row within 16-row chunk
  int skb = (lane & 3) * 8;      // bf16 element offset within 32-elem row
  const unsigned short* gA = hbf + (size_t)(m0 + srow) * Dc + skb;
  const unsigned short* gB = Wt + (size_t)(n0 + srow) * Dc + skb;

  int fr = lane & 15, kg = (lane >> 4) * 8;

  for (int k0 = 0; k0 < Dc; k0 += 32) {
#pragma unroll
    for (int cc = 0; cc < 2; ++cc) {
      int c = wave + cc * 4;
      __builtin_amdgcn_global_load_lds(
          (const __attribute__((address_space(1))) void*)(gA + (size_t)c * 16 * Dc + k0),
          (__attribute__((address_space(3))) void*)(As + c * 16 * 32), 16, 0, 0);
      __builtin_amdgcn_global_load_lds(
          (const __attribute__((address_space(1))) void*)(gB + (size_t)c * 16 * Dc + k0),
          (__attribute__((address_space(3))) void*)(Bs + c * 16 * 32), 16, 0, 0);
    }
    __syncthreads();

    bf16x8 af[4], bfr[4];
#pragma unroll
    for (int m = 0; m < 4; ++m)
      af[m] = *(const bf16x8*)(As + (wr * 64 + m * 16 + fr) * 32 + kg);
#pragma unroll
    for (int n = 0; n < 4; ++n)
      bfr[n] = *(const bf16x8*)(Bs + (wc * 64 + n * 16 + fr) * 32 + kg);
#pragma unroll
    for (int m = 0; m < 4; ++m)
#pragma unroll
      for (int n = 0; n < 4; ++n)
        acc[m][n] = __builtin_amdgcn_mfma_f32_16x16x32_bf16(af[m], bfr[n], acc[m][n], 0, 0, 0);
    __syncthreads();
  }

  // epilogue: C/D mapping col=lane&15, row=(lane>>4)*4+r  [m89-verified]
  int fq = lane >> 4;
#pragma unroll
  for (int m = 0; m < 4; ++m) {
#pragma unroll
    for (int n = 0; n < 4; ++n) {
      int col = n0 + wc * 64 + n * 16 + fr;
      float bb = bias[col];
#pragma unroll
      for (int r = 0; r < 4; ++r) {
        int row = m0 + wr * 64 + m * 16 + fq * 4 + r;
        C[(size_t)row * Dc + col] = acc[m][n][r] + bb;
      }
    }
  }
}

// ---------------------------------------------------------------------------
// scores[b,h,q,k] = (Q.K)/8 + Wspe[spe[b,q,k]][h] + mask[b,k]  (fp32)
// ---------------------------------------------------------------------------
__global__ __launch_bounds__(256) void k_scores(
    const float* __restrict__ Q, const float* __restrict__ K,
    const int* __restrict__ spe, const float* __restrict__ Wspe,
    const float* __restrict__ mask, float* __restrict__ probs) {
  int bh = blockIdx.z;
  int b = bh >> 4, h = bh & 15;
  int q0 = blockIdx.y * 64, k0 = blockIdx.x * 64;
  __shared__ float Qs[64][64];   // [qrow][dh]
  __shared__ float Kst[64][64];  // [dh][kcol]
  int tid = threadIdx.x;
  for (int i = tid; i < 64 * 16; i += 256) {
    int row = i >> 4, c4 = (i & 15) * 4;
    float4 v = *(const float4*)(Q + (size_t)(b * Sc + q0 + row) * Dc + h * DHc + c4);
    *(float4*)&Qs[row][c4] = v;
  }
  for (int i = tid; i < 64 * 16; i += 256) {
    int row = i >> 4, c4 = (i & 15) * 4;
    float4 v = *(const float4*)(K + (size_t)(b * Sc + k0 + row) * Dc + h * DHc + c4);
    Kst[c4 + 0][row] = v.x;
    Kst[c4 + 1][row] = v.y;
    Kst[c4 + 2][row] = v.z;
    Kst[c4 + 3][row] = v.w;
  }
  __syncthreads();
  int tx = tid & 15, ty = tid >> 4;
  float acc[4][4] = {};
#pragma unroll 16
  for (int dh = 0; dh < 64; ++dh) {
    float a0 = Qs[ty * 4 + 0][dh];
    float a1 = Qs[ty * 4 + 1][dh];
    float a2 = Qs[ty * 4 + 2][dh];
    float a3 = Qs[ty * 4 + 3][dh];
    float4 b4 = *(float4*)&Kst[dh][tx * 4];
    acc[0][0] += a0 * b4.x; acc[0][1] += a0 * b4.y; acc[0][2] += a0 * b4.z; acc[0][3] += a0 * b4.w;
    acc[1][0] += a1 * b4.x; acc[1][1] += a1 * b4.y; acc[1][2] += a1 * b4.z; acc[1][3] += a1 * b4.w;
    acc[2][0] += a2 * b4.x; acc[2][1] += a2 * b4.y; acc[2][2] += a2 * b4.z; acc[2][3] += a2 * b4.w;
    acc[3][0] += a3 * b4.x; acc[3][1] += a3 * b4.y; acc[3][2] += a3 * b4.z; acc[3][3] += a3 * b4.w;
  }
  const float scale = 0.125f;
  float4 mk = *(const float4*)(mask + b * Sc + k0 + tx * 4);
#pragma unroll
  for (int i = 0; i < 4; ++i) {
    int qrow = q0 + ty * 4 + i;
    int4 sp = *(const int4*)(spe + ((size_t)b * Sc + qrow) * Sc + k0 + tx * 4);
    float4 r;
    r.x = acc[i][0] * scale + Wspe[sp.x * Hc + h] + mk.x;
    r.y = acc[i][1] * scale + Wspe[sp.y * Hc + h] + mk.y;
    r.z = acc[i][2] * scale + Wspe[sp.z * Hc + h] + mk.z;
    r.w = acc[i][3] * scale + Wspe[sp.w * Hc + h] + mk.w;
    *(float4*)(probs + ((size_t)bh * Sc + qrow) * Sc + k0 + tx * 4) = r;
  }
}

// ---------------------------------------------------------------------------
// in-place row softmax over 512; one wave per row
// ---------------------------------------------------------------------------
__global__ __launch_bounds__(256) void k_softmax(float* __restrict__ probs) {
  size_t row = ((size_t)blockIdx.x * 256 + threadIdx.x) >> 6;
  int lane = threadIdx.x & 63;
  float* p = probs + row * Sc;
  float4 x0 = ((float4*)p)[lane];
  float4 x1 = ((float4*)p)[lane + 64];
  float m = fmaxf(fmaxf(fmaxf(x0.x, x0.y), fmaxf(x0.z, x0.w)),
                  fmaxf(fmaxf(x1.x, x1.y), fmaxf(x1.z, x1.w)));
#pragma unroll
  for (int o = 32; o; o >>= 1) m = fmaxf(m, __shfl_xor(m, o));
  x0.x = __expf(x0.x - m); x0.y = __expf(x0.y - m);
  x0.z = __expf(x0.z - m); x0.w = __expf(x0.w - m);
  x1.x = __expf(x1.x - m); x1.y = __expf(x1.y - m);
  x1.z = __expf(x1.z - m); x1.w = __expf(x1.w - m);
  float s = x0.x + x0.y + x0.z + x0.w + x1.x + x1.y + x1.z + x1.w;
#pragma unroll
  for (int o = 32; o; o >>= 1) s += __shfl_xor(s, o);
  float r = 1.f / s;
  x0.x *= r; x0.y *= r; x0.z *= r; x0.w *= r;
  x1.x *= r; x1.y *= r; x1.z *= r; x1.w *= r;
  ((float4*)p)[lane] = x0;
  ((float4*)p)[lane + 64] = x1;
}

// ---------------------------------------------------------------------------
// ctx[b,q,h*64+dh] = sum_k probs[b,h,q,k] * V[b,k,h*64+dh]
// ---------------------------------------------------------------------------
__global__ __launch_bounds__(256) void k_pv(
    const float* __restrict__ probs, const float* __restrict__ V,
    float* __restrict__ ctx) {
  int bh = blockIdx.z;
  int b = bh >> 4, h = bh & 15;
  int q0 = blockIdx.x * 64;
  __shared__ float Ps[64][64];
  __shared__ float Vs[64][64];
  int tid = threadIdx.x;
  int tx = tid & 15, ty = tid >> 4;
  float acc[4][4] = {};
  for (int k0 = 0; k0 < Sc; k0 += 64) {
    for (int i = tid; i < 64 * 16; i += 256) {
      int row = i >> 4, c4 = (i & 15) * 4;
      *(float4*)&Ps[row][c4] =
          *(const float4*)(probs + ((size_t)bh * Sc + q0 + row) * Sc + k0 + c4);
      *(float4*)&Vs[row][c4] =
          *(const float4*)(V + (size_t)(b * Sc + k0 + row) * Dc + h * DHc + c4);
    }
    __syncthreads();
#pragma unroll 16
    for (int kk = 0; kk < 64; ++kk) {
      float a0 = Ps[ty * 4 + 0][kk];
      float a1 = Ps[ty * 4 + 1][kk];
      float a2 = Ps[ty * 4 + 2][kk];
      float a3 = Ps[ty * 4 + 3][kk];
      float4 b4 = *(float4*)&Vs[kk][tx * 4];
      acc[0][0] += a0 * b4.x; acc[0][1] += a0 * b4.y; acc[0][2] += a0 * b4.z; acc[0][3] += a0 * b4.w;
      acc[1][0] += a1 * b4.x; acc[1][1] += a1 * b4.y; acc[1][2] += a1 * b4.z; acc[1][3] += a1 * b4.w;
      acc[2][0] += a2 * b4.x; acc[2][1] += a2 * b4.y; acc[2][2] += a2 * b4.z; acc[2][3] += a2 * b4.w;
      acc[3][0] += a3 * b4.x; acc[3][1] += a3 * b4.y; acc[3][2] += a3 * b4.z; acc[3][3] += a3 * b4.w;
    }
    __syncthreads();
  }
#pragma unroll
  for (int i = 0; i < 4; ++i) {
    *(float4*)(ctx + (size_t)(b * Sc + q0 + ty * 4 + i) * Dc + h * DHc + tx * 4) =
        make_float4(acc[i][0], acc[i][1], acc[i][2], acc[i][3]);
  }
}

extern "C" void kernel_launch(void* const* d_in, const int* in_sizes, int n_in,
                              void* d_out, int out_size, void* d_ws, size_t ws_size,
                              hipStream_t stream) {
  const float* hidden = (const float*)d_in[0];
  const float* amask = (const float*)d_in[1];
  const int* ind = (const int*)d_in[3];
  const int* outd = (const int*)d_in[4];
  const int* spe = (const int*)d_in[5];
  const float* Wq = (const float*)d_in[8];
  const float* bq = (const float*)d_in[9];
  const float* Wk = (const float*)d_in[10];
  const float* bk = (const float*)d_in[11];
  const float* Wv = (const float*)d_in[12];
  const float* bv = (const float*)d_in[13];
  const float* Win = (const float*)d_in[14];
  const float* Wout = (const float*)d_in[15];
  const float* Wspe = (const float*)d_in[16];

  char* ws = (char*)d_ws;
  const size_t BSD = (size_t)Bc * Sc * Dc;  // 8388608
  unsigned short* hbf = (unsigned short*)ws;                    // 16 MB
  unsigned short* Wtq = (unsigned short*)(ws + 16u * 1048576);  // 2 MB
  unsigned short* Wtk = (unsigned short*)(ws + 18u * 1048576);  // 2 MB
  unsigned short* Wtv = (unsigned short*)(ws + 20u * 1048576);  // 2 MB
  float* Q = (float*)(ws + 24u * 1048576);                      // 32 MB
  float* K = (float*)(ws + 56u * 1048576);                      // 32 MB
  float* V = (float*)(ws + 88u * 1048576);                      // 32 MB
  float* ctx = (float*)d_out;
  float* probs = (float*)d_out + BSD;

  k_pos_add<<<dim3(Bc * Sc), 256, 0, stream>>>(hidden, ind, outd, Win, Wout, hbf);
  k_wt<<<dim3(16, 16, 3), 256, 0, stream>>>(Wq, Wk, Wv, Wtq, Wtk, Wtv);
  k_gemm_mfma<<<dim3(8, 64, 3), 256, 0, stream>>>(hbf, Wtq, bq, Wtk, bk, Wtv, bv, Q, K, V);
  k_scores<<<dim3(8, 8, Bc * Hc), 256, 0, stream>>>(Q, K, spe, Wspe, amask, probs);
  k_softmax<<<dim3((Bc * Hc * Sc) / 4), 256, 0, stream>>>(probs);
  k_pv<<<dim3(8, 1, Bc * Hc), 256, 0, stream>>>(probs, V, ctx);
}

// Round 3
// 434.076 us; speedup vs baseline: 2.6461x; 1.2789x over previous
//
#include <hip/hip_runtime.h>

#define Bc 16
#define Sc 512
#define Dc 1024
#define Hc 16
#define DHc 64

typedef __attribute__((ext_vector_type(8))) __bf16 bf16x8;
typedef __attribute__((ext_vector_type(4))) float f32x4;
typedef __attribute__((ext_vector_type(8))) unsigned short ushort8;

static __device__ __forceinline__ unsigned short f2bf(float f) {
  unsigned int u = __builtin_bit_cast(unsigned int, f);
  unsigned int r = (u + 0x7fffu + ((u >> 16) & 1u)) >> 16;  // RNE
  return (unsigned short)r;
}

// ---------------------------------------------------------------------------
// h_bf16 = bf16( hidden + (W_in*padmask)[in_degree] + (W_out*padmask)[out_degree] )
// ---------------------------------------------------------------------------
__global__ __launch_bounds__(256) void k_pos_add(
    const float* __restrict__ hidden, const int* __restrict__ ind,
    const int* __restrict__ outd, const float* __restrict__ Win,
    const float* __restrict__ Wout, unsigned short* __restrict__ hbf) {
  int row = blockIdx.x;
  int t = threadIdx.x;
  int id = ind[row], od = outd[row];
  float fi = (id != 0) ? 1.f : 0.f;
  float fo = (od != 0) ? 1.f : 0.f;
  float4 a = ((const float4*)(hidden + (size_t)row * Dc))[t];
  float4 x = ((const float4*)(Win + (size_t)id * Dc))[t];
  float4 y = ((const float4*)(Wout + (size_t)od * Dc))[t];
  ushort4 r;
  r.x = f2bf(a.x + fi * x.x + fo * y.x);
  r.y = f2bf(a.y + fi * x.y + fo * y.y);
  r.z = f2bf(a.z + fi * x.z + fo * y.z);
  r.w = f2bf(a.w + fi * x.w + fo * y.w);
  ((ushort4*)(hbf + (size_t)row * Dc))[t] = r;
}

// ---------------------------------------------------------------------------
// Wt[n][k] = bf16(W[k][n]) for q,k,v
// ---------------------------------------------------------------------------
__global__ __launch_bounds__(256) void k_wt(
    const float* __restrict__ Wq, const float* __restrict__ Wk,
    const float* __restrict__ Wv, unsigned short* __restrict__ Wtq,
    unsigned short* __restrict__ Wtk, unsigned short* __restrict__ Wtv) {
  const float* W = blockIdx.z == 0 ? Wq : blockIdx.z == 1 ? Wk : Wv;
  unsigned short* Wt = blockIdx.z == 0 ? Wtq : blockIdx.z == 1 ? Wtk : Wtv;
  __shared__ float tile[64][65];
  int k0 = blockIdx.y * 64, n0 = blockIdx.x * 64;
  int r = threadIdx.x >> 4, c4 = (threadIdx.x & 15) * 4;
  for (int rr = r; rr < 64; rr += 16) {
    float4 v = *(const float4*)(W + (size_t)(k0 + rr) * Dc + n0 + c4);
    tile[rr][c4 + 0] = v.x;
    tile[rr][c4 + 1] = v.y;
    tile[rr][c4 + 2] = v.z;
    tile[rr][c4 + 3] = v.w;
  }
  __syncthreads();
  for (int rr = r; rr < 64; rr += 16) {
    ushort4 o;
    o.x = f2bf(tile[c4 + 0][rr]);
    o.y = f2bf(tile[c4 + 1][rr]);
    o.z = f2bf(tile[c4 + 2][rr]);
    o.w = f2bf(tile[c4 + 3][rr]);
    *(ushort4*)(Wt + (size_t)(n0 + rr) * Dc + k0 + c4) = o;
  }
}

// ---------------------------------------------------------------------------
// QKV projections, bf16 MFMA, bf16 outputs. 128x128 tile, BK=32, 4 waves.
// ---------------------------------------------------------------------------
__global__ __launch_bounds__(256) void k_gemm_mfma(
    const unsigned short* __restrict__ hbf,
    const unsigned short* __restrict__ Wtq, const float* __restrict__ bq,
    const unsigned short* __restrict__ Wtk, const float* __restrict__ bk,
    const unsigned short* __restrict__ Wtv, const float* __restrict__ bv,
    unsigned short* __restrict__ Qo, unsigned short* __restrict__ Ko,
    unsigned short* __restrict__ Vo) {
  const unsigned short* Wt;
  const float* bias;
  unsigned short* C;
  if (blockIdx.z == 0) { Wt = Wtq; bias = bq; C = Qo; }
  else if (blockIdx.z == 1) { Wt = Wtk; bias = bk; C = Ko; }
  else { Wt = Wtv; bias = bv; C = Vo; }

  __shared__ __align__(16) unsigned short As[128 * 32];
  __shared__ __align__(16) unsigned short Bs[128 * 32];

  int tid = threadIdx.x, lane = tid & 63, wave = tid >> 6;
  int m0 = blockIdx.y * 128, n0 = blockIdx.x * 128;
  int wr = wave >> 1, wc = wave & 1;

  f32x4 acc[4][4] = {};

  int srow = lane >> 2;
  int skb = (lane & 3) * 8;
  const unsigned short* gA = hbf + (size_t)(m0 + srow) * Dc + skb;
  const unsigned short* gB = Wt + (size_t)(n0 + srow) * Dc + skb;

  int fr = lane & 15, kg = (lane >> 4) * 8;

  for (int k0 = 0; k0 < Dc; k0 += 32) {
#pragma unroll
    for (int cc = 0; cc < 2; ++cc) {
      int c = wave + cc * 4;
      __builtin_amdgcn_global_load_lds(
          (const __attribute__((address_space(1))) void*)(gA + (size_t)c * 16 * Dc + k0),
          (__attribute__((address_space(3))) void*)(As + c * 16 * 32), 16, 0, 0);
      __builtin_amdgcn_global_load_lds(
          (const __attribute__((address_space(1))) void*)(gB + (size_t)c * 16 * Dc + k0),
          (__attribute__((address_space(3))) void*)(Bs + c * 16 * 32), 16, 0, 0);
    }
    __syncthreads();

    bf16x8 af[4], bfr[4];
#pragma unroll
    for (int m = 0; m < 4; ++m)
      af[m] = *(const bf16x8*)(As + (wr * 64 + m * 16 + fr) * 32 + kg);
#pragma unroll
    for (int n = 0; n < 4; ++n)
      bfr[n] = *(const bf16x8*)(Bs + (wc * 64 + n * 16 + fr) * 32 + kg);
#pragma unroll
    for (int m = 0; m < 4; ++m)
#pragma unroll
      for (int n = 0; n < 4; ++n)
        acc[m][n] = __builtin_amdgcn_mfma_f32_16x16x32_bf16(af[m], bfr[n], acc[m][n], 0, 0, 0);
    __syncthreads();
  }

  int fq = lane >> 4;
#pragma unroll
  for (int m = 0; m < 4; ++m) {
#pragma unroll
    for (int n = 0; n < 4; ++n) {
      int col = n0 + wc * 64 + n * 16 + fr;
      float bb = bias[col];
#pragma unroll
      for (int r = 0; r < 4; ++r) {
        int row = m0 + wr * 64 + m * 16 + fq * 4 + r;
        C[(size_t)row * Dc + col] = f2bf(acc[m][n][r] + bb);
      }
    }
  }
}

// ---------------------------------------------------------------------------
// Fused attention: per block = (b, h, 64 q-rows).
// QK^T (MFMA) -> S[64][516] fp32 in LDS -> bias(spe)+mask -> softmax ->
// probs write (once) -> PV (MFMA) with 1/l folded into ctx epilogue.
// dynamic LDS = 152832 B -> 1 block/CU.
// ---------------------------------------------------------------------------
#define SW 516
__global__ __launch_bounds__(256) void k_attn(
    const unsigned short* __restrict__ Qb, const unsigned short* __restrict__ Kb,
    const unsigned short* __restrict__ Vb, const int* __restrict__ spe,
    const float* __restrict__ Wspe, const float* __restrict__ mask,
    float* __restrict__ probs, float* __restrict__ ctx) {
  extern __shared__ char smem[];
  float* S = (float*)smem;                                       // 64*516*4 = 132096
  unsigned short* Kt = (unsigned short*)(smem + 132096);         // [64][72] = 9216
  unsigned short* Vt = (unsigned short*)(smem + 132096 + 9216);  // [64][72] = 9216
  float* Wb = (float*)(smem + 132096 + 18432);                   // [512] = 2048
  float* Rinv = (float*)(smem + 132096 + 18432 + 2048);          // [64]

  int tid = threadIdx.x, lane = tid & 63, w = tid >> 6;
  int fr = lane & 15, fq = lane >> 4, kg8 = fq * 8;

  // XCD-chunked swizzle: each XCD owns a contiguous swz range (2 b's)
  int flat = blockIdx.x;
  int swz = (flat & 7) * 256 + (flat >> 3);
  int h = swz & 15, qt = (swz >> 4) & 7, b = swz >> 7;
  int q0 = qt * 64;

  // Wspe column for this head -> LDS
  for (int i = tid; i < 512; i += 256) Wb[i] = Wspe[i * Hc + h];

  // Q A-fragments straight from global (held in regs for whole QK^T phase)
  const unsigned short* qbase = Qb + (size_t)(b * Sc + q0) * Dc + h * DHc;
  bf16x8 af[4][2];
#pragma unroll
  for (int m = 0; m < 4; ++m)
#pragma unroll
    for (int kk = 0; kk < 2; ++kk)
      af[m][kk] = *(const bf16x8*)(qbase + (size_t)(m * 16 + fr) * Dc + kk * 32 + kg8);

  // ---- QK^T ----
  const unsigned short* kbase = Kb + (size_t)(b * Sc) * Dc + h * DHc;
  for (int kt = 0; kt < 8; ++kt) {
    for (int i = tid; i < 512; i += 256) {
      int row = i >> 3, g = i & 7;
      *(ushort8*)(Kt + row * 72 + g * 8) =
          *(const ushort8*)(kbase + (size_t)(kt * 64 + row) * Dc + g * 8);
    }
    __syncthreads();
    f32x4 acc[4] = {};
#pragma unroll
    for (int kk = 0; kk < 2; ++kk) {
      bf16x8 bfrag = *(const bf16x8*)(Kt + (w * 16 + fr) * 72 + kk * 32 + kg8);
#pragma unroll
      for (int m = 0; m < 4; ++m)
        acc[m] = __builtin_amdgcn_mfma_f32_16x16x32_bf16(af[m][kk], bfrag, acc[m], 0, 0, 0);
    }
#pragma unroll
    for (int m = 0; m < 4; ++m)
#pragma unroll
      for (int r = 0; r < 4; ++r)
        S[(m * 16 + fq * 4 + r) * SW + kt * 64 + w * 16 + fr] = acc[m][r] * 0.125f;
    __syncthreads();
  }

  // ---- softmax (row = w*16 + lane/4; 4 lanes per row, 128 cols each) ----
  int srow = w * 16 + (lane >> 2);
  int chunk = lane & 3;
  float* sp = S + srow * SW + chunk * 128;
  const int* spp = spe + (size_t)(b * Sc + q0 + srow) * Sc + chunk * 128;
  const float* mkp = mask + b * Sc + chunk * 128;
  float mx = -3.4e38f;
#pragma unroll 4
  for (int j = 0; j < 32; ++j) {
    float4 s = *(float4*)(sp + j * 4);
    int4 si = *(const int4*)(spp + j * 4);
    float4 mk = *(const float4*)(mkp + j * 4);
    s.x += Wb[si.x] + mk.x;
    s.y += Wb[si.y] + mk.y;
    s.z += Wb[si.z] + mk.z;
    s.w += Wb[si.w] + mk.w;
    mx = fmaxf(mx, fmaxf(fmaxf(s.x, s.y), fmaxf(s.z, s.w)));
    *(float4*)(sp + j * 4) = s;
  }
  mx = fmaxf(mx, __shfl_xor(mx, 1));
  mx = fmaxf(mx, __shfl_xor(mx, 2));
  float sum = 0.f;
#pragma unroll 4
  for (int j = 0; j < 32; ++j) {
    float4 s = *(float4*)(sp + j * 4);
    s.x = __expf(s.x - mx);
    s.y = __expf(s.y - mx);
    s.z = __expf(s.z - mx);
    s.w = __expf(s.w - mx);
    sum += s.x + s.y + s.z + s.w;
    *(float4*)(sp + j * 4) = s;
  }
  sum += __shfl_xor(sum, 1);
  sum += __shfl_xor(sum, 2);
  float rinv = 1.f / sum;
  if ((lane & 3) == 0) Rinv[srow] = rinv;
  __syncthreads();

  // ---- probs write (coalesced, normalized) ----
  float* pbase = probs + (size_t)((b * Hc + h) * Sc + q0) * Sc;
  for (int i = tid; i < 64 * 128; i += 256) {
    int row = i >> 7, c4 = (i & 127) * 4;
    float4 e = *(float4*)(S + row * SW + c4);
    float rv = Rinv[row];
    e.x *= rv; e.y *= rv; e.z *= rv; e.w *= rv;
    *(float4*)(pbase + (size_t)row * Sc + c4) = e;
  }

  // ---- PV (unnormalized exp from LDS; 1/l in epilogue) ----
  const unsigned short* vbase = Vb + (size_t)(b * Sc) * Dc + h * DHc;
  int vk = lane;
  int dhb = w * 16;
  f32x4 pacc[4] = {};
  for (int kt = 0; kt < 8; ++kt) {
    ushort8 v0 = *(const ushort8*)(vbase + (size_t)(kt * 64 + vk) * Dc + dhb);
    ushort8 v1 = *(const ushort8*)(vbase + (size_t)(kt * 64 + vk) * Dc + dhb + 8);
#pragma unroll
    for (int jj = 0; jj < 8; ++jj) {
      Vt[(dhb + jj) * 72 + vk] = v0[jj];
      Vt[(dhb + 8 + jj) * 72 + vk] = v1[jj];
    }
    __syncthreads();
#pragma unroll
    for (int kk = 0; kk < 2; ++kk) {
      bf16x8 bfrag = *(const bf16x8*)(Vt + (w * 16 + fr) * 72 + kk * 32 + kg8);
#pragma unroll
      for (int m = 0; m < 4; ++m) {
        const float* s2 = S + (m * 16 + fr) * SW + kt * 64 + kk * 32 + kg8;
        float4 a0 = *(const float4*)(s2);
        float4 a1 = *(const float4*)(s2 + 4);
        bf16x8 afr;
        afr[0] = (__bf16)a0.x; afr[1] = (__bf16)a0.y;
        afr[2] = (__bf16)a0.z; afr[3] = (__bf16)a0.w;
        afr[4] = (__bf16)a1.x; afr[5] = (__bf16)a1.y;
        afr[6] = (__bf16)a1.z; afr[7] = (__bf16)a1.w;
        pacc[m] = __builtin_amdgcn_mfma_f32_16x16x32_bf16(afr, bfrag, pacc[m], 0, 0, 0);
      }
    }
    __syncthreads();
  }
  float* cbase = ctx + (size_t)(b * Sc + q0) * Dc + h * DHc + w * 16 + fr;
#pragma unroll
  for (int m = 0; m < 4; ++m)
#pragma unroll
    for (int r = 0; r < 4; ++r) {
      int row = m * 16 + fq * 4 + r;
      cbase[(size_t)row * Dc] = pacc[m][r] * Rinv[row];
    }
}

extern "C" void kernel_launch(void* const* d_in, const int* in_sizes, int n_in,
                              void* d_out, int out_size, void* d_ws, size_t ws_size,
                              hipStream_t stream) {
  const float* hidden = (const float*)d_in[0];
  const float* amask = (const float*)d_in[1];
  const int* ind = (const int*)d_in[3];
  const int* outd = (const int*)d_in[4];
  const int* spe = (const int*)d_in[5];
  const float* Wq = (const float*)d_in[8];
  const float* bq = (const float*)d_in[9];
  const float* Wk = (const float*)d_in[10];
  const float* bk = (const float*)d_in[11];
  const float* Wv = (const float*)d_in[12];
  const float* bv = (const float*)d_in[13];
  const float* Win = (const float*)d_in[14];
  const float* Wout = (const float*)d_in[15];
  const float* Wspe = (const float*)d_in[16];

  char* ws = (char*)d_ws;
  const size_t BSD = (size_t)Bc * Sc * Dc;
  unsigned short* hbf = (unsigned short*)ws;                    // 16 MB
  unsigned short* Wtq = (unsigned short*)(ws + 16u * 1048576);  // 2 MB
  unsigned short* Wtk = (unsigned short*)(ws + 18u * 1048576);  // 2 MB
  unsigned short* Wtv = (unsigned short*)(ws + 20u * 1048576);  // 2 MB
  unsigned short* Qb = (unsigned short*)(ws + 24u * 1048576);   // 16 MB
  unsigned short* Kb = (unsigned short*)(ws + 40u * 1048576);   // 16 MB
  unsigned short* Vb = (unsigned short*)(ws + 56u * 1048576);   // 16 MB
  float* ctx = (float*)d_out;
  float* probs = (float*)d_out + BSD;

  hipFuncSetAttribute((const void*)k_attn,
                      hipFuncAttributeMaxDynamicSharedMemorySize, 152832);

  k_pos_add<<<dim3(Bc * Sc), 256, 0, stream>>>(hidden, ind, outd, Win, Wout, hbf);
  k_wt<<<dim3(16, 16, 3), 256, 0, stream>>>(Wq, Wk, Wv, Wtq, Wtk, Wtv);
  k_gemm_mfma<<<dim3(8, 64, 3), 256, 0, stream>>>(hbf, Wtq, bq, Wtk, bk, Wtv, bv, Qb, Kb, Vb);
  k_attn<<<dim3(2048), 256, 152832, stream>>>(Qb, Kb, Vb, spe, Wspe, amask, probs, ctx);
}

// Round 4
// 310.881 us; speedup vs baseline: 3.6947x; 1.3963x over previous
//
#include <hip/hip_runtime.h>

#define Bc 16
#define Sc 512
#define Dc 1024
#define Hc 16
#define DHc 64

typedef __attribute__((ext_vector_type(8))) __bf16 bf16x8;
typedef __attribute__((ext_vector_type(4))) float f32x4;
typedef __attribute__((ext_vector_type(8))) unsigned short ushort8;

static __device__ __forceinline__ unsigned short f2bf(float f) {
  unsigned int u = __builtin_bit_cast(unsigned int, f);
  unsigned int r = (u + 0x7fffu + ((u >> 16) & 1u)) >> 16;  // RNE
  return (unsigned short)r;
}

// ---------------------------------------------------------------------------
// h_bf16 = bf16( hidden + (W_in*padmask)[in_degree] + (W_out*padmask)[out_degree] )
// ---------------------------------------------------------------------------
__global__ __launch_bounds__(256) void k_pos_add(
    const float* __restrict__ hidden, const int* __restrict__ ind,
    const int* __restrict__ outd, const float* __restrict__ Win,
    const float* __restrict__ Wout, unsigned short* __restrict__ hbf) {
  int row = blockIdx.x;
  int t = threadIdx.x;
  int id = ind[row], od = outd[row];
  float fi = (id != 0) ? 1.f : 0.f;
  float fo = (od != 0) ? 1.f : 0.f;
  float4 a = ((const float4*)(hidden + (size_t)row * Dc))[t];
  float4 x = ((const float4*)(Win + (size_t)id * Dc))[t];
  float4 y = ((const float4*)(Wout + (size_t)od * Dc))[t];
  ushort4 r;
  r.x = f2bf(a.x + fi * x.x + fo * y.x);
  r.y = f2bf(a.y + fi * x.y + fo * y.y);
  r.z = f2bf(a.z + fi * x.z + fo * y.z);
  r.w = f2bf(a.w + fi * x.w + fo * y.w);
  ((ushort4*)(hbf + (size_t)row * Dc))[t] = r;
}

// ---------------------------------------------------------------------------
// Wt[n][k] = bf16(W[k][n]) for q,k,v
// ---------------------------------------------------------------------------
__global__ __launch_bounds__(256) void k_wt(
    const float* __restrict__ Wq, const float* __restrict__ Wk,
    const float* __restrict__ Wv, unsigned short* __restrict__ Wtq,
    unsigned short* __restrict__ Wtk, unsigned short* __restrict__ Wtv) {
  const float* W = blockIdx.z == 0 ? Wq : blockIdx.z == 1 ? Wk : Wv;
  unsigned short* Wt = blockIdx.z == 0 ? Wtq : blockIdx.z == 1 ? Wtk : Wtv;
  __shared__ float tile[64][65];
  int k0 = blockIdx.y * 64, n0 = blockIdx.x * 64;
  int r = threadIdx.x >> 4, c4 = (threadIdx.x & 15) * 4;
  for (int rr = r; rr < 64; rr += 16) {
    float4 v = *(const float4*)(W + (size_t)(k0 + rr) * Dc + n0 + c4);
    tile[rr][c4 + 0] = v.x;
    tile[rr][c4 + 1] = v.y;
    tile[rr][c4 + 2] = v.z;
    tile[rr][c4 + 3] = v.w;
  }
  __syncthreads();
  for (int rr = r; rr < 64; rr += 16) {
    ushort4 o;
    o.x = f2bf(tile[c4 + 0][rr]);
    o.y = f2bf(tile[c4 + 1][rr]);
    o.z = f2bf(tile[c4 + 2][rr]);
    o.w = f2bf(tile[c4 + 3][rr]);
    *(ushort4*)(Wt + (size_t)(n0 + rr) * Dc + k0 + c4) = o;
  }
}

// ---------------------------------------------------------------------------
// QKV projections, bf16 MFMA, bf16 outputs. 128x128 tile, BK=32, 4 waves.
// ---------------------------------------------------------------------------
__global__ __launch_bounds__(256) void k_gemm_mfma(
    const unsigned short* __restrict__ hbf,
    const unsigned short* __restrict__ Wtq, const float* __restrict__ bq,
    const unsigned short* __restrict__ Wtk, const float* __restrict__ bk,
    const unsigned short* __restrict__ Wtv, const float* __restrict__ bv,
    unsigned short* __restrict__ Qo, unsigned short* __restrict__ Ko,
    unsigned short* __restrict__ Vo) {
  const unsigned short* Wt;
  const float* bias;
  unsigned short* C;
  if (blockIdx.z == 0) { Wt = Wtq; bias = bq; C = Qo; }
  else if (blockIdx.z == 1) { Wt = Wtk; bias = bk; C = Ko; }
  else { Wt = Wtv; bias = bv; C = Vo; }

  __shared__ __align__(16) unsigned short As[128 * 32];
  __shared__ __align__(16) unsigned short Bs[128 * 32];

  int tid = threadIdx.x, lane = tid & 63, wave = tid >> 6;
  int m0 = blockIdx.y * 128, n0 = blockIdx.x * 128;
  int wr = wave >> 1, wc = wave & 1;

  f32x4 acc[4][4] = {};

  int srow = lane >> 2;
  int skb = (lane & 3) * 8;
  const unsigned short* gA = hbf + (size_t)(m0 + srow) * Dc + skb;
  const unsigned short* gB = Wt + (size_t)(n0 + srow) * Dc + skb;

  int fr = lane & 15, kg = (lane >> 4) * 8;

  for (int k0 = 0; k0 < Dc; k0 += 32) {
#pragma unroll
    for (int cc = 0; cc < 2; ++cc) {
      int c = wave + cc * 4;
      __builtin_amdgcn_global_load_lds(
          (const __attribute__((address_space(1))) void*)(gA + (size_t)c * 16 * Dc + k0),
          (__attribute__((address_space(3))) void*)(As + c * 16 * 32), 16, 0, 0);
      __builtin_amdgcn_global_load_lds(
          (const __attribute__((address_space(1))) void*)(gB + (size_t)c * 16 * Dc + k0),
          (__attribute__((address_space(3))) void*)(Bs + c * 16 * 32), 16, 0, 0);
    }
    __syncthreads();

    bf16x8 af[4], bfr[4];
#pragma unroll
    for (int m = 0; m < 4; ++m)
      af[m] = *(const bf16x8*)(As + (wr * 64 + m * 16 + fr) * 32 + kg);
#pragma unroll
    for (int n = 0; n < 4; ++n)
      bfr[n] = *(const bf16x8*)(Bs + (wc * 64 + n * 16 + fr) * 32 + kg);
#pragma unroll
    for (int m = 0; m < 4; ++m)
#pragma unroll
      for (int n = 0; n < 4; ++n)
        acc[m][n] = __builtin_amdgcn_mfma_f32_16x16x32_bf16(af[m], bfr[n], acc[m][n], 0, 0, 0);
    __syncthreads();
  }

  int fq = lane >> 4;
#pragma unroll
  for (int m = 0; m < 4; ++m) {
#pragma unroll
    for (int n = 0; n < 4; ++n) {
      int col = n0 + wc * 64 + n * 16 + fr;
      float bb = bias[col];
#pragma unroll
      for (int r = 0; r < 4; ++r) {
        int row = m0 + wr * 64 + m * 16 + fq * 4 + r;
        C[(size_t)row * Dc + col] = f2bf(acc[m][n][r] + bb);
      }
    }
  }
}

// ---------------------------------------------------------------------------
// Fused attention: per block = (b, h, 32 q-rows). 4 waves, 77440 B LDS
// -> 2 blocks/CU (8 waves/CU). probs write folded into the PV loop.
// ---------------------------------------------------------------------------
#define SW 516
#define QB 32
__global__ __launch_bounds__(256) void k_attn(
    const unsigned short* __restrict__ Qb, const unsigned short* __restrict__ Kb,
    const unsigned short* __restrict__ Vb, const int* __restrict__ spe,
    const float* __restrict__ Wspe, const float* __restrict__ mask,
    float* __restrict__ probs, float* __restrict__ ctx) {
  extern __shared__ char smem[];
  float* S = (float*)smem;                                 // 32*516*4 = 66048
  unsigned short* KVt = (unsigned short*)(smem + 66048);   // [64][72] = 9216
  float* Wb = (float*)(smem + 66048 + 9216);               // [512] = 2048
  float* Rinv = (float*)(smem + 66048 + 9216 + 2048);      // [32]

  int tid = threadIdx.x, lane = tid & 63, w = tid >> 6;
  int fr = lane & 15, fq = lane >> 4, kg8 = fq * 8;
  int qh = w & 1, wh = w >> 1;  // q-half / (k-half in QK^T, dh-half in PV)

  // XCD-chunked swizzle; qt fastest -> consecutive blocks share (b,h) K/V
  int flat = blockIdx.x;
  int swz = (flat & 7) * 512 + (flat >> 3);
  int qt = swz & 15, h = (swz >> 4) & 15, b = swz >> 8;
  int q0 = qt * QB;

  for (int i = tid; i < 512; i += 256) Wb[i] = Wspe[i * Hc + h];

  // Q A-fragments in registers for the whole QK^T phase
  const unsigned short* qbase = Qb + (size_t)(b * Sc + q0) * Dc + h * DHc;
  bf16x8 af[2];
#pragma unroll
  for (int kk = 0; kk < 2; ++kk)
    af[kk] = *(const bf16x8*)(qbase + (size_t)(qh * 16 + fr) * Dc + kk * 32 + kg8);

  // ---- QK^T : 8 iterations of 64 k-rows ----
  const unsigned short* kbase = Kb + (size_t)(b * Sc) * Dc + h * DHc;
  for (int it = 0; it < 8; ++it) {
    {  // stage 64x64 K rows -> KVt[row][72]
      int r = tid >> 2, c = (tid & 3) * 16;
      const unsigned short* src = kbase + (size_t)(it * 64 + r) * Dc + c;
      *(ushort8*)(KVt + r * 72 + c) = *(const ushort8*)(src);
      *(ushort8*)(KVt + r * 72 + c + 8) = *(const ushort8*)(src + 8);
    }
    __syncthreads();
#pragma unroll
    for (int nf = 0; nf < 2; ++nf) {
      f32x4 acc = {};
#pragma unroll
      for (int kk = 0; kk < 2; ++kk) {
        bf16x8 bfrag = *(const bf16x8*)(KVt + (wh * 32 + nf * 16 + fr) * 72 + kk * 32 + kg8);
        acc = __builtin_amdgcn_mfma_f32_16x16x32_bf16(af[kk], bfrag, acc, 0, 0, 0);
      }
#pragma unroll
      for (int r = 0; r < 4; ++r)
        S[(qh * 16 + fq * 4 + r) * SW + it * 64 + wh * 32 + nf * 16 + fr] = acc[r] * 0.125f;
    }
    __syncthreads();
  }

  // ---- bias + mask + softmax: 8 lanes per row, 64 cols each ----
  int srow = tid >> 3;
  int chunk = tid & 7;
  float* sp = S + srow * SW + chunk * 64;
  const int* spp = spe + (size_t)(b * Sc + q0 + srow) * Sc + chunk * 64;
  const float* mkp = mask + b * Sc + chunk * 64;
  float mx = -3.4e38f;
#pragma unroll 4
  for (int j = 0; j < 16; ++j) {
    float4 s = *(float4*)(sp + j * 4);
    int4 si = *(const int4*)(spp + j * 4);
    float4 mk = *(const float4*)(mkp + j * 4);
    s.x += Wb[si.x] + mk.x;
    s.y += Wb[si.y] + mk.y;
    s.z += Wb[si.z] + mk.z;
    s.w += Wb[si.w] + mk.w;
    mx = fmaxf(mx, fmaxf(fmaxf(s.x, s.y), fmaxf(s.z, s.w)));
    *(float4*)(sp + j * 4) = s;
  }
  mx = fmaxf(mx, __shfl_xor(mx, 1));
  mx = fmaxf(mx, __shfl_xor(mx, 2));
  mx = fmaxf(mx, __shfl_xor(mx, 4));
  float sum = 0.f;
#pragma unroll 4
  for (int j = 0; j < 16; ++j) {
    float4 s = *(float4*)(sp + j * 4);
    s.x = __expf(s.x - mx);
    s.y = __expf(s.y - mx);
    s.z = __expf(s.z - mx);
    s.w = __expf(s.w - mx);
    sum += s.x + s.y + s.z + s.w;
    *(float4*)(sp + j * 4) = s;
  }
  sum += __shfl_xor(sum, 1);
  sum += __shfl_xor(sum, 2);
  sum += __shfl_xor(sum, 4);
  if ((tid & 7) == 0) Rinv[srow] = 1.f / sum;
  __syncthreads();

  // ---- PV + interleaved probs write; 1/l folded into epilogues ----
  const unsigned short* vbase = Vb + (size_t)(b * Sc) * Dc + h * DHc;
  float* pbase = probs + (size_t)((b * Hc + h) * Sc + q0) * Sc;
  f32x4 pacc[2] = {};
  for (int it = 0; it < 8; ++it) {
    {  // stage V transposed: KVt[dh][k]
      int vk = tid & 63, dhb = (tid >> 6) * 16;
      const unsigned short* src = vbase + (size_t)(it * 64 + vk) * Dc + dhb;
      ushort8 v0 = *(const ushort8*)(src);
      ushort8 v1 = *(const ushort8*)(src + 8);
#pragma unroll
      for (int jj = 0; jj < 8; ++jj) {
        KVt[(dhb + jj) * 72 + vk] = v0[jj];
        KVt[(dhb + 8 + jj) * 72 + vk] = v1[jj];
      }
    }
    __syncthreads();
    {  // overlapped probs write for this 64-col slab (fire-and-forget)
      int row = tid >> 3, c0 = (tid & 7) * 8;
      float rv = Rinv[row];
      float4 e0 = *(float4*)(S + row * SW + it * 64 + c0);
      float4 e1 = *(float4*)(S + row * SW + it * 64 + c0 + 4);
      e0.x *= rv; e0.y *= rv; e0.z *= rv; e0.w *= rv;
      e1.x *= rv; e1.y *= rv; e1.z *= rv; e1.w *= rv;
      *(float4*)(pbase + (size_t)row * Sc + it * 64 + c0) = e0;
      *(float4*)(pbase + (size_t)row * Sc + it * 64 + c0 + 4) = e1;
    }
#pragma unroll
    for (int kk = 0; kk < 2; ++kk) {
      const float* s2 = S + (qh * 16 + fr) * SW + it * 64 + kk * 32 + kg8;
      float4 a0 = *(const float4*)(s2);
      float4 a1 = *(const float4*)(s2 + 4);
      bf16x8 afr;
      afr[0] = (__bf16)a0.x; afr[1] = (__bf16)a0.y;
      afr[2] = (__bf16)a0.z; afr[3] = (__bf16)a0.w;
      afr[4] = (__bf16)a1.x; afr[5] = (__bf16)a1.y;
      afr[6] = (__bf16)a1.z; afr[7] = (__bf16)a1.w;
#pragma unroll
      for (int nf = 0; nf < 2; ++nf) {
        bf16x8 bfrag = *(const bf16x8*)(KVt + (wh * 32 + nf * 16 + fr) * 72 + kk * 32 + kg8);
        pacc[nf] = __builtin_amdgcn_mfma_f32_16x16x32_bf16(afr, bfrag, pacc[nf], 0, 0, 0);
      }
    }
    __syncthreads();
  }
  float* cbase = ctx + (size_t)(b * Sc + q0 + qh * 16) * Dc + h * DHc + wh * 32;
#pragma unroll
  for (int nf = 0; nf < 2; ++nf)
#pragma unroll
    for (int r = 0; r < 4; ++r) {
      int row = fq * 4 + r;
      cbase[(size_t)row * Dc + nf * 16 + fr] = pacc[nf][r] * Rinv[qh * 16 + row];
    }
}

extern "C" void kernel_launch(void* const* d_in, const int* in_sizes, int n_in,
                              void* d_out, int out_size, void* d_ws, size_t ws_size,
                              hipStream_t stream) {
  const float* hidden = (const float*)d_in[0];
  const float* amask = (const float*)d_in[1];
  const int* ind = (const int*)d_in[3];
  const int* outd = (const int*)d_in[4];
  const int* spe = (const int*)d_in[5];
  const float* Wq = (const float*)d_in[8];
  const float* bq = (const float*)d_in[9];
  const float* Wk = (const float*)d_in[10];
  const float* bk = (const float*)d_in[11];
  const float* Wv = (const float*)d_in[12];
  const float* bv = (const float*)d_in[13];
  const float* Win = (const float*)d_in[14];
  const float* Wout = (const float*)d_in[15];
  const float* Wspe = (const float*)d_in[16];

  char* ws = (char*)d_ws;
  const size_t BSD = (size_t)Bc * Sc * Dc;
  unsigned short* hbf = (unsigned short*)ws;                    // 16 MB
  unsigned short* Wtq = (unsigned short*)(ws + 16u * 1048576);  // 2 MB
  unsigned short* Wtk = (unsigned short*)(ws + 18u * 1048576);  // 2 MB
  unsigned short* Wtv = (unsigned short*)(ws + 20u * 1048576);  // 2 MB
  unsigned short* Qb = (unsigned short*)(ws + 24u * 1048576);   // 16 MB
  unsigned short* Kb = (unsigned short*)(ws + 40u * 1048576);   // 16 MB
  unsigned short* Vb = (unsigned short*)(ws + 56u * 1048576);   // 16 MB
  float* ctx = (float*)d_out;
  float* probs = (float*)d_out + BSD;

  hipFuncSetAttribute((const void*)k_attn,
                      hipFuncAttributeMaxDynamicSharedMemorySize, 77440);

  k_pos_add<<<dim3(Bc * Sc), 256, 0, stream>>>(hidden, ind, outd, Win, Wout, hbf);
  k_wt<<<dim3(16, 16, 3), 256, 0, stream>>>(Wq, Wk, Wv, Wtq, Wtk, Wtv);
  k_gemm_mfma<<<dim3(8, 64, 3), 256, 0, stream>>>(hbf, Wtq, bq, Wtk, bk, Wtv, bv, Qb, Kb, Vb);
  k_attn<<<dim3(4096), 256, 77440, stream>>>(Qb, Kb, Vb, spe, Wspe, amask, probs, ctx);
}